// Round 15
// baseline (37.763 us; speedup 1.0000x reference)
//
#include <hip/hip_runtime.h>
#include <hip/hip_bf16.h>
#include <stdint.h>

#define C_ 400
#define TINV 10.0f
#define ALPHA_ 0.03f

typedef __bf16 bf16x8 __attribute__((ext_vector_type(8)));
typedef float f32x4 __attribute__((ext_vector_type(4)));

__device__ __forceinline__ void load16(const void* g, void* l) {
  __builtin_amdgcn_global_load_lds(
      (const __attribute__((address_space(1))) uint32_t*)g,
      (__attribute__((address_space(3))) uint32_t*)l, 16, 0, 0);
}

// ---- K0: convert features f32->bf16 (row-permuted new_r=(r%8)*512+r/8, float4
//          vectorized) + CE partials (8 rows/block) + zero S1/S2 + counter reset.
__global__ __launch_bounds__(256) void k_prep(const float* __restrict__ feat,
                                              const float* __restrict__ predicts,
                                              const int* __restrict__ labels,
                                              uint16_t* __restrict__ featB,
                                              float* __restrict__ Sz,  // S1||S2
                                              double* __restrict__ p_ce,
                                              unsigned int* __restrict__ counter) {
  __shared__ double smr[4];
  const int t = threadIdx.x, bid = blockIdx.x;
  const int lane = t & 63, w = t >> 6;
  if (bid == 0 && t == 0) counter[0] = 0;

  int zi = bid * 256 + t;
  if (zi < 65536) Sz[zi] = 0.f;  // zero S1 (32768 f32) and S2 (32768 f32)

  int idx4 = bid * 256 + t;  // 131072 float4 tasks
  int nr = idx4 >> 5, d4 = idx4 & 31;
  int r = ((nr & 511) << 3) | (nr >> 9);
  float4 v = reinterpret_cast<const float4*>(feat)[r * 32 + d4];
  __hip_bfloat16 h0 = __float2bfloat16(v.x), h1 = __float2bfloat16(v.y),
                 h2 = __float2bfloat16(v.z), h3 = __float2bfloat16(v.w);
  ushort4 o;
  o.x = *(uint16_t*)&h0; o.y = *(uint16_t*)&h1;
  o.z = *(uint16_t*)&h2; o.w = *(uint16_t*)&h3;
  reinterpret_cast<ushort4*>(featB)[idx4] = o;

  double ce = 0.0;
#pragma unroll
  for (int s = 0; s < 2; ++s) {
    int row = bid * 8 + w * 2 + s;
    const float* pr = predicts + (size_t)row * C_;
    float mx = -3.0e38f;
    for (int k = lane; k < C_; k += 64) mx = fmaxf(mx, pr[k]);
#pragma unroll
    for (int o2 = 32; o2; o2 >>= 1) mx = fmaxf(mx, __shfl_xor(mx, o2));
    float sum = 0.f;
    for (int k = lane; k < C_; k += 64) sum += __expf(pr[k] - mx);
#pragma unroll
    for (int o2 = 32; o2; o2 >>= 1) sum += __shfl_xor(sum, o2);
    ce += (double)(__logf(sum) + mx - pr[labels[row]]);
  }
  if (lane == 0) smr[w] = ce;
  __syncthreads();
  if (t == 0) p_ce[bid] = smr[0] + smr[1] + smr[2] + smr[3];
}

// ---- K1: SYMMETRIC Gram sweep. 128x128 tiles on the 32x32 chunk grid; only
// cr<=cc computed (528 active blocks of 1024 launched; lower triangle exits).
// B-tile (cc chunk, 32KB) staged once via global_load_lds (st-swizzle
// byte^=((row&7)<<4), inverse-swizzled source); A-frags (cr chunk, wave's 32
// rows) direct from L2-resident featB (verified one-time pattern). Each exp'd
// element feeds row-sums (shfl row-reduce, verified) AND for cr<cc the
// transposed row's sums via column-reduce (in-lane q/rg sum + shfl_xor 16/32 +
// LDS cross-wave). Accumulation: f32 atomicAdd into zeroed S1/S2[g][8]
// (order jitter ~1e-6 << 0.27 threshold). P written exactly once per entry
// (direct + mirror in upper tiles; Egg on diag tiles, true diagonal zeroed
// from sums — verified semantics).
__global__ __launch_bounds__(256, 4) void k_sym(const uint16_t* __restrict__ featB,
                                                float* __restrict__ S1,
                                                float* __restrict__ S2,
                                                float* __restrict__ P) {
  __shared__ alignas(16) uint16_t Bt[128 * 128];
  __shared__ float colP[4][2][128];
  const int t = threadIdx.x, bid = blockIdx.x;
  const int cr = bid >> 5, cc = bid & 31;
  if (cr > cc) return;
  const int lane = t & 63, w = t >> 6;
  const int r0 = lane & 15, kq = lane >> 4, rq = kq << 2;
  const char* fb = (const char*)featB;
  const int rb = cr << 7, cb = cc << 7;
  const int ib = cr >> 2, jb = cc >> 2;
  const bool diag = (cr == cc);

  // Stage B-tile: 128 col-rows x 256 B = 32 KB.
#pragma unroll
  for (int it = 0; it < 8; ++it) {
    int L = it * 4096 + t * 16;
    int row = L >> 8;
    int kbs = (L & 255) ^ ((row & 7) << 4);
    load16(fb + (size_t)(cb + row) * 256 + kbs, (char*)Bt + L);
  }
  // A fragments: wave's 32 rows, direct from L2 (overlaps staging drain).
  bf16x8 a[2][4];
#pragma unroll
  for (int rg = 0; rg < 2; ++rg) {
    const size_t ra = (size_t)(rb + w * 32 + rg * 16 + r0) * 256 + kq * 16;
#pragma unroll
    for (int kk = 0; kk < 4; ++kk) a[rg][kk] = *(const bf16x8*)(fb + ra + kk * 64);
  }
  __syncthreads();

  float s1[2][4], s2[2][4];
#pragma unroll
  for (int rg = 0; rg < 2; ++rg)
#pragma unroll
    for (int q = 0; q < 4; ++q) { s1[rg][q] = 0.f; s2[rg][q] = 0.f; }
  float cs1[8], cs2[8];
#pragma unroll
  for (int n = 0; n < 8; ++n) { cs1[n] = 0.f; cs2[n] = 0.f; }

#pragma unroll
  for (int n = 0; n < 8; ++n) {
    const int cl = n * 16 + r0;
    bf16x8 bn[4];
#pragma unroll
    for (int kk = 0; kk < 4; ++kk)
      bn[kk] = *(const bf16x8*)((const char*)Bt + cl * 256 +
                                ((kk * 64 + kq * 16) ^ ((cl & 7) << 4)));
    f32x4 acc[2];
    acc[0] = (f32x4)0.0f;
    acc[1] = (f32x4)0.0f;
#pragma unroll
    for (int rg = 0; rg < 2; ++rg)
#pragma unroll
      for (int kk = 0; kk < 4; ++kk)
        acc[rg] = __builtin_amdgcn_mfma_f32_16x16x32_bf16(a[rg][kk], bn[kk],
                                                          acc[rg], 0, 0, 0);
#pragma unroll
    for (int rg = 0; rg < 2; ++rg)
#pragma unroll
      for (int q = 0; q < 4; ++q) {
        float e = __expf(acc[rg][q] * TINV);
        int grow = rb + w * 32 + rg * 16 + rq + q;
        int gcol = cb + n * 16 + r0;
        if (diag) {
          if (gcol == grow) {
            P[(size_t)grow * 8 + jb] = e;  // Egg
            e = 0.f;                       // exclude true diagonal
          }
        } else if ((gcol & 511) == (grow & 511)) {
          P[(size_t)grow * 8 + jb] = e;    // direct partner
          P[(size_t)gcol * 8 + ib] = e;    // mirrored partner (unique writer)
        }
        s1[rg][q] += e;
        s2[rg][q] += e * e;
        cs1[n] += e;
        cs2[n] += e * e;
      }
  }

  // Row-sum contributions (rows of chunk cr over cols of chunk cc).
#pragma unroll
  for (int rg = 0; rg < 2; ++rg)
#pragma unroll
    for (int q = 0; q < 4; ++q) {
      float v1 = s1[rg][q], v2 = s2[rg][q];
#pragma unroll
      for (int o2 = 1; o2 <= 8; o2 <<= 1) {
        v1 += __shfl_xor(v1, o2);
        v2 += __shfl_xor(v2, o2);
      }
      if (r0 == 0) {
        int grow = rb + w * 32 + rg * 16 + rq + q;
        atomicAdd(&S1[(size_t)grow * 8 + jb], v1);
        atomicAdd(&S2[(size_t)grow * 8 + jb], v2);
      }
    }

  // Column-sum contributions (rows of chunk cc over cols of chunk cr) — only
  // for strictly-upper tiles (diag would double count).
  if (!diag) {
#pragma unroll
    for (int n = 0; n < 8; ++n) {
      float v1 = cs1[n], v2 = cs2[n];
      v1 += __shfl_xor(v1, 16); v1 += __shfl_xor(v1, 32);
      v2 += __shfl_xor(v2, 16); v2 += __shfl_xor(v2, 32);
      if (lane < 16) {
        colP[w][0][n * 16 + lane] = v1;
        colP[w][1][n * 16 + lane] = v2;
      }
    }
    __syncthreads();
    if (t < 128) {
      float v1 = colP[0][0][t] + colP[1][0][t] + colP[2][0][t] + colP[3][0][t];
      float v2 = colP[0][1][t] + colP[1][1][t] + colP[2][1][t] + colP[3][1][t];
      atomicAdd(&S1[(size_t)(cb + t) * 8 + ib], v1);
      atomicAdd(&S2[(size_t)(cb + t) * 8 + ib], v2);
    }
  }
}

// ---- K2: closed-form NCE from power sums (S1,S2 single-slot), 128 blocks;
// deterministic last-block finalize (atomic counter, reset by k_prep).
__global__ __launch_bounds__(256) void k_post(const float* __restrict__ S1,
                                              const float* __restrict__ S2,
                                              const float* __restrict__ P,
                                              const double* __restrict__ p_ce,
                                              double* __restrict__ p_nce,
                                              unsigned int* __restrict__ counter,
                                              float* __restrict__ out) {
  __shared__ double smr[4];
  __shared__ int isLast;
  const int t = threadIdx.x, b = blockIdx.x;
  const int lane = t & 63, w = t >> 6;
  double nce = 0.0;
  {
    int task = b * 256 + t;  // 0..32767
    int g = task >> 3, j = task & 7, i = g >> 9;
    float s1i = S1[(size_t)g * 8 + i];
    float s2i = S2[(size_t)g * 8 + i];
    float Egg = P[(size_t)g * 8 + i];
    float val;
    if (j != i) {
      float s1j = S1[(size_t)g * 8 + j];
      float s2j = S2[(size_t)g * 8 + j];
      float div = s1i + s1j;
      float inv = 1.f / div;
      float pmt = P[(size_t)g * 8 + j] * inv;
      float Ls = (s1i + s1j) + inv * (0.5f * (s2i + s2j));
      val = __logf(pmt) - __logf(1.f - pmt) - inv * Ls;
    } else {
      float div = 2.f * s1i + Egg;
      float inv = 1.f / div;
      float pmt = Egg * inv;
      float Ls = s1i + inv * (0.5f * s2i);
      val = 2.f * __logf(pmt) - 4.f * inv * Ls;
    }
    nce = (double)val;
  }
#pragma unroll
  for (int o2 = 32; o2; o2 >>= 1) nce += __shfl_xor(nce, o2);
  if (lane == 0) smr[w] = nce;
  __syncthreads();
  if (t == 0) {
    p_nce[b] = smr[0] + smr[1] + smr[2] + smr[3];
    __threadfence();
    unsigned int old = atomicAdd(counter, 1u);
    isLast = (old == 127u) ? 1 : 0;
  }
  __syncthreads();
  if (isLast) {
    __threadfence();
    double tn = (t < 128) ? p_nce[t] : 0.0;
    double tc = p_ce[t] + p_ce[t + 256];
#pragma unroll
    for (int o2 = 32; o2; o2 >>= 1) {
      tn += __shfl_xor(tn, o2);
      tc += __shfl_xor(tc, o2);
    }
    __shared__ double smn2[4], smc2[4];
    if (lane == 0) { smn2[w] = tn; smc2[w] = tc; }
    __syncthreads();
    if (t == 0) {
      double fn = smn2[0] + smn2[1] + smn2[2] + smn2[3];
      double fc = smc2[0] + smc2[1] + smc2[2] + smc2[3];
      out[0] = ALPHA_ * (-(float)(fn / 1024.0)) + (float)(fc / 4096.0);
    }
  }
}

__global__ void k_sentinel(float* out) {
  if (threadIdx.x == 0) out[0] = 12345.0f;
}

extern "C" void kernel_launch(void* const* d_in, const int* in_sizes, int n_in,
                              void* d_out, int out_size, void* d_ws, size_t ws_size,
                              hipStream_t stream) {
  const float* predicts = (const float*)d_in[0];
  const int* labels = (const int*)d_in[1];
  const float* features = (const float*)d_in[2];

  char* ws = (char*)d_ws;
  const size_t offS1 = 0;                    // 4096*8*4 = 128 KiB
  const size_t offS2 = offS1 + 131072;       // 128 KiB (contiguous with S1)
  const size_t offFeatB = offS2 + 131072;    // 1 MiB
  const size_t offP = offFeatB + 1048576;    // 128 KiB
  const size_t offCe = offP + 131072;        // 512 doubles
  const size_t offNce = offCe + 4096;        // 128 doubles
  const size_t offCnt = offNce + 1024;       // 1 uint
  const size_t need = offCnt + 64;

  float* out = (float*)d_out;
  if (ws_size < need) {
    k_sentinel<<<1, 64, 0, stream>>>(out);
    return;
  }

  float* S1 = (float*)(ws + offS1);
  float* S2 = (float*)(ws + offS2);
  uint16_t* featB = (uint16_t*)(ws + offFeatB);
  float* P = (float*)(ws + offP);
  double* p_ce = (double*)(ws + offCe);
  double* p_nce = (double*)(ws + offNce);
  unsigned int* counter = (unsigned int*)(ws + offCnt);

  k_prep<<<512, 256, 0, stream>>>(features, predicts, labels, featB, S1, p_ce,
                                  counter);
  k_sym<<<1024, 256, 0, stream>>>(featB, S1, S2, P);
  k_post<<<128, 256, 0, stream>>>(S1, S2, P, p_ce, p_nce, counter, out);
}